// Round 2
// 598.540 us; speedup vs baseline: 1.1195x; 1.1195x over previous
//
#include <hip/hip_runtime.h>
#include <hip/hip_bf16.h>
#include <math.h>

#define N_NODES 131072
#define N_EDGES 1048576
#define B_GR    128
#define NPG_    1024
#define KTOP    30

// ---------------- CSR build ----------------

__global__ __launch_bounds__(256) void k_zero(int* cnt) {
    int i = blockIdx.x * 256 + threadIdx.x;
    if (i < N_NODES) cnt[i] = 0;
}

__global__ __launch_bounds__(256) void k_count(const int* __restrict__ dst, int* __restrict__ cnt) {
    int e = blockIdx.x * 256 + threadIdx.x;
    if (e < N_EDGES) atomicAdd(&cnt[dst[e]], 1);
}

__global__ __launch_bounds__(256) void k_scan1(const int* __restrict__ cnt,
                                               int* __restrict__ row_start,
                                               int* __restrict__ blocksum) {
    __shared__ int s[256];
    int t = threadIdx.x;
    int i = blockIdx.x * 256 + t;
    int v = cnt[i];
    s[t] = v; __syncthreads();
    for (int o = 1; o < 256; o <<= 1) {
        int x = (t >= o) ? s[t - o] : 0;
        __syncthreads();
        s[t] += x;
        __syncthreads();
    }
    row_start[i] = s[t] - v;
    if (t == 255) blocksum[blockIdx.x] = s[t];
}

__global__ __launch_bounds__(512) void k_scan2(int* __restrict__ blocksum) {
    __shared__ int s[512];
    int t = threadIdx.x;
    int v = blocksum[t];
    s[t] = v; __syncthreads();
    for (int o = 1; o < 512; o <<= 1) {
        int x = (t >= o) ? s[t - o] : 0;
        __syncthreads();
        s[t] += x;
        __syncthreads();
    }
    blocksum[t] = s[t] - v;
}

__global__ __launch_bounds__(256) void k_scan3(int* __restrict__ row_start,
                                               const int* __restrict__ blocksum,
                                               int* __restrict__ cursor) {
    int i = blockIdx.x * 256 + threadIdx.x;
    int r = row_start[i] + blocksum[blockIdx.x];
    row_start[i] = r;
    cursor[i] = r;
}

// csr[pos] = (src, eid) packed — one 8-B scatter instead of two 4-B
__global__ __launch_bounds__(256) void k_fill(const int* __restrict__ src,
                                              const int* __restrict__ dst,
                                              int* __restrict__ cursor,
                                              int2* __restrict__ csr) {
    int e = blockIdx.x * 256 + threadIdx.x;
    if (e < N_EDGES) {
        int d = dst[e];
        int pos = atomicAdd(&cursor[d], 1);
        csr[pos] = make_int2(src[e], e);
    }
}

// ---------------- esum[n][32] = sum of incident edge_feat rows ----------------
// 4 nodes per 32-lane group; all id loads then all row gathers issued
// back-to-back => ~64 cache lines in flight per wave during the burst.

__global__ __launch_bounds__(256) void k_esum(const float* __restrict__ ef,
                                              const int* __restrict__ row_start,
                                              const int* __restrict__ cnt,
                                              const int2* __restrict__ csr,
                                              float* __restrict__ esum) {
    int g = threadIdx.x >> 5, j = threadIdx.x & 31;
    int n0 = (blockIdx.x * 8 + g) * 4;
    int st[4], ln[4];
    #pragma unroll
    for (int i = 0; i < 4; ++i) { st[i] = row_start[n0 + i]; ln[i] = cnt[n0 + i]; }
    float acc[4] = {0.f, 0.f, 0.f, 0.f};
    int base = 0;
    while ((ln[0] > base) | (ln[1] > base) | (ln[2] > base) | (ln[3] > base)) {
        int eid[4][8];
        #pragma unroll
        for (int i = 0; i < 4; ++i) {
            #pragma unroll
            for (int s = 0; s < 8; ++s) {
                int idx = base + s;
                int a = st[i] + ((idx < ln[i]) ? idx : 0);
                a = (a < N_EDGES) ? a : 0;
                eid[i][s] = csr[a].y;          // uniform within group
            }
        }
        #pragma unroll
        for (int i = 0; i < 4; ++i) {
            #pragma unroll
            for (int s = 0; s < 8; ++s) {
                float v = ef[(size_t)eid[i][s] * 32 + j];
                acc[i] += ((base + s) < ln[i]) ? v : 0.f;
            }
        }
        base += 8;
    }
    #pragma unroll
    for (int i = 0; i < 4; ++i)
        esum[(size_t)(n0 + i) * 32 + j] = acc[i];
}

// ---------------- z0 = [nf | esum] @ W0   (K=160, SGPR weights, lane=node)

__global__ __launch_bounds__(256) void k_gemm160(const float* __restrict__ nf,
                                                 const float* __restrict__ esum,
                                                 const float* __restrict__ W0,
                                                 float* __restrict__ z0) {
    __shared__ float a[64 * 161];
    int tid = threadIdx.x;
    int n0 = blockIdx.x * 64;
    const float* nfb = nf + (size_t)n0 * 128;
    for (int f = tid; f < 8192; f += 256) {
        int n = f >> 7, k = f & 127;
        a[n * 161 + k] = nfb[f];
    }
    const float* esb = esum + (size_t)n0 * 32;
    for (int f = tid; f < 2048; f += 256) {
        int n = f >> 5, k = f & 31;
        a[n * 161 + 128 + k] = esb[f];
    }
    __syncthreads();
    int wv = __builtin_amdgcn_readfirstlane(tid >> 6);
    int lane = tid & 63;
    int c0 = wv * 8;
    float acc[8] = {0.f, 0.f, 0.f, 0.f, 0.f, 0.f, 0.f, 0.f};
    const float* ar = a + lane * 161;
    for (int k = 0; k < 160; ++k) {
        float av = ar[k];
        #pragma unroll
        for (int jj = 0; jj < 8; ++jj)
            acc[jj] += av * W0[k * 32 + c0 + jj];
    }
    float* zr = z0 + (size_t)(n0 + lane) * 32 + c0;
    *(float4*)zr = make_float4(acc[0], acc[1], acc[2], acc[3]);
    *(float4*)(zr + 4) = make_float4(acc[4], acc[5], acc[6], acc[7]);
}

// ---------------- fused propagation layer ----------------
// h = tanh((z_self + sum z_nb + b)/deg) ; z_next = h @ Wn
// 4 nodes per 32-lane group (lane = feature); batched id+gather rounds;
// gemm fused via lane-broadcast shuffles against LDS-staged Wn.

__global__ __launch_bounds__(256) void k_layer(const float* __restrict__ zin,
                                               const int* __restrict__ row_start,
                                               const int* __restrict__ cnt,
                                               const int2* __restrict__ csr,
                                               const float* __restrict__ bias,
                                               const float* __restrict__ Wn,
                                               float* __restrict__ hout,
                                               float* __restrict__ znext) {
    __shared__ float Ws[1024];
    int tid = threadIdx.x;
    for (int f = tid; f < 1024; f += 256) Ws[f] = Wn[f];
    __syncthreads();
    int g = tid >> 5, j = tid & 31;
    int n0 = (blockIdx.x * 8 + g) * 4;
    int st[4], ln[4];
    #pragma unroll
    for (int i = 0; i < 4; ++i) { st[i] = row_start[n0 + i]; ln[i] = cnt[n0 + i]; }
    float acc[4];
    #pragma unroll
    for (int i = 0; i < 4; ++i) acc[i] = zin[(size_t)(n0 + i) * 32 + j];  // self
    int base = 0;
    while ((ln[0] > base) | (ln[1] > base) | (ln[2] > base) | (ln[3] > base)) {
        int sid[4][8];
        #pragma unroll
        for (int i = 0; i < 4; ++i) {
            #pragma unroll
            for (int s = 0; s < 8; ++s) {
                int idx = base + s;
                int a = st[i] + ((idx < ln[i]) ? idx : 0);
                a = (a < N_EDGES) ? a : 0;
                sid[i][s] = csr[a].x;          // src node id, uniform within group
            }
        }
        #pragma unroll
        for (int i = 0; i < 4; ++i) {
            #pragma unroll
            for (int s = 0; s < 8; ++s) {
                float v = zin[(size_t)sid[i][s] * 32 + j];
                acc[i] += ((base + s) < ln[i]) ? v : 0.f;
            }
        }
        base += 8;
    }
    float bj = bias[j];
    float h[4];
    #pragma unroll
    for (int i = 0; i < 4; ++i) {
        float deg = 1.f + (float)ln[i];
        h[i] = tanhf((acc[i] + bj) / deg);
        hout[(size_t)(n0 + i) * 32 + j] = h[i];
    }
    float z[4] = {0.f, 0.f, 0.f, 0.f};
    for (int k = 0; k < 32; ++k) {
        float w = Ws[k * 32 + j];
        #pragma unroll
        for (int i = 0; i < 4; ++i)
            z[i] += __shfl(h[i], k, 32) * w;
    }
    #pragma unroll
    for (int i = 0; i < 4; ++i)
        znext[(size_t)(n0 + i) * 32 + j] = z[i];
}

// ---------------- last 32-wide layer: h2 + scalar z3 = h2 @ W3 ----------------

__global__ __launch_bounds__(256) void k_layer3(const float* __restrict__ zin,
                                                const int* __restrict__ row_start,
                                                const int* __restrict__ cnt,
                                                const int2* __restrict__ csr,
                                                const float* __restrict__ bias,
                                                const float* __restrict__ W3,
                                                float* __restrict__ hout,
                                                float* __restrict__ z3) {
    int g = threadIdx.x >> 5, j = threadIdx.x & 31;
    int n0 = (blockIdx.x * 8 + g) * 4;
    int st[4], ln[4];
    #pragma unroll
    for (int i = 0; i < 4; ++i) { st[i] = row_start[n0 + i]; ln[i] = cnt[n0 + i]; }
    float acc[4];
    #pragma unroll
    for (int i = 0; i < 4; ++i) acc[i] = zin[(size_t)(n0 + i) * 32 + j];
    int base = 0;
    while ((ln[0] > base) | (ln[1] > base) | (ln[2] > base) | (ln[3] > base)) {
        int sid[4][8];
        #pragma unroll
        for (int i = 0; i < 4; ++i) {
            #pragma unroll
            for (int s = 0; s < 8; ++s) {
                int idx = base + s;
                int a = st[i] + ((idx < ln[i]) ? idx : 0);
                a = (a < N_EDGES) ? a : 0;
                sid[i][s] = csr[a].x;
            }
        }
        #pragma unroll
        for (int i = 0; i < 4; ++i) {
            #pragma unroll
            for (int s = 0; s < 8; ++s) {
                float v = zin[(size_t)sid[i][s] * 32 + j];
                acc[i] += ((base + s) < ln[i]) ? v : 0.f;
            }
        }
        base += 8;
    }
    float bj = bias[j];
    float w3 = W3[j];
    #pragma unroll
    for (int i = 0; i < 4; ++i) {
        float deg = 1.f + (float)ln[i];
        float h = tanhf((acc[i] + bj) / deg);
        hout[(size_t)(n0 + i) * 32 + j] = h;
        float t = h * w3;
        #pragma unroll
        for (int o = 16; o; o >>= 1) t += __shfl_xor(t, o, 32);
        if (j == 0) z3[n0 + i] = t;
    }
}

// ---------------- layer 3: scalar gather-sum -> val ----------------

__global__ __launch_bounds__(256) void k_g3(const float* __restrict__ z3,
                                            const int* __restrict__ row_start,
                                            const int* __restrict__ cnt,
                                            const int2* __restrict__ csr,
                                            const float* __restrict__ b3,
                                            float* __restrict__ val) {
    int n = blockIdx.x * 256 + threadIdx.x;
    int start = row_start[n], len = cnt[n];
    const int2* cs = csr + start;
    float s = z3[n];
    int i = 0;
    for (; i + 4 <= len; i += 4)
        s += z3[cs[i].x] + z3[cs[i + 1].x] + z3[cs[i + 2].x] + z3[cs[i + 3].x];
    for (; i < len; ++i) s += z3[cs[i].x];
    float deg = 1.f + (float)len;
    val[n] = tanhf((s + b3[0]) / deg);
}

// ---------------- top-k + conv head, one block per graph ----------------

__global__ __launch_bounds__(256) void k_head(const float* __restrict__ h0,
                                              const float* __restrict__ h1,
                                              const float* __restrict__ h2,
                                              const float* __restrict__ val,
                                              const float* __restrict__ wc1,
                                              const float* __restrict__ bc1,
                                              const float* __restrict__ wc2,
                                              const float* __restrict__ bc2,
                                              const float* __restrict__ wout,
                                              const float* __restrict__ bout,
                                              float* __restrict__ out) {
    __shared__ float vals[1024];
    __shared__ int selidx[KTOP];
    __shared__ float sp[KTOP * 97];
    __shared__ float y1[16 * 30];
    __shared__ float pool[16 * 15];
    __shared__ float y2[352];
    int b = blockIdx.x, tid = threadIdx.x;
    const float* vb = val + (size_t)b * NPG_;
    for (int u = tid; u < NPG_; u += 256) vals[u] = vb[u];
    __syncthreads();
    if (tid < 64) {
        unsigned long long keys[16];
        #pragma unroll
        for (int r = 0; r < 16; ++r) {
            int u = tid * 16 + r;
            unsigned int bb = __float_as_uint(vals[u]);
            unsigned int ord = (bb & 0x80000000u) ? ~bb : (bb | 0x80000000u);
            keys[r] = ((unsigned long long)ord << 32) |
                      (unsigned long long)(0xFFFFFFFFu - (unsigned int)u);
        }
        for (int k = 0; k < KTOP; ++k) {
            unsigned long long m = keys[0];
            #pragma unroll
            for (int r = 1; r < 16; ++r) m = (keys[r] > m) ? keys[r] : m;
            #pragma unroll
            for (int o = 32; o; o >>= 1) {
                unsigned long long t = __shfl_xor(m, o);
                m = (t > m) ? t : m;
            }
            int u = (int)(0xFFFFFFFFu - (unsigned int)(m & 0xFFFFFFFFull));
            if (tid == 0) selidx[k] = u;
            #pragma unroll
            for (int r = 0; r < 16; ++r)
                if (tid * 16 + r == u) keys[r] = 0ull;
        }
    }
    __syncthreads();
    size_t nb = (size_t)b * NPG_;
    for (int idx = tid; idx < KTOP * 32; idx += 256) {
        int t = idx >> 5, d = idx & 31;
        size_t s = (nb + (size_t)selidx[t]) * 32;
        sp[t * 97 + d]      = h0[s + d];
        sp[t * 97 + 32 + d] = h1[s + d];
        sp[t * 97 + 64 + d] = h2[s + d];
    }
    if (tid < KTOP) sp[tid * 97 + 96] = vb[selidx[tid]];
    __syncthreads();
    for (int idx = tid; idx < 480; idx += 256) {
        int t = idx >> 4, c = idx & 15;
        float acc = bc1[c];
        for (int d = 0; d < 97; ++d) acc += sp[t * 97 + d] * wc1[c * 97 + d];
        y1[c * 30 + t] = fmaxf(acc, 0.f);
    }
    __syncthreads();
    for (int idx = tid; idx < 240; idx += 256) {
        int c = idx / 15, u = idx - c * 15;
        pool[c * 15 + u] = fmaxf(y1[c * 30 + 2 * u], y1[c * 30 + 2 * u + 1]);
    }
    __syncthreads();
    for (int idx = tid; idx < 352; idx += 256) {
        int o = idx / 11, t = idx - o * 11;
        float acc = bc2[o];
        for (int i = 0; i < 16; ++i)
            for (int kk = 0; kk < 5; ++kk)
                acc += pool[i * 15 + t + kk] * wc2[(o * 16 + i) * 5 + kk];
        y2[idx] = fmaxf(acc, 0.f);
    }
    __syncthreads();
    if (tid < 2) {
        float acc = bout[tid];
        for (int m = 0; m < 352; ++m) acc += y2[m] * wout[m * 2 + tid];
        out[b * 2 + tid] = fmaxf(acc, 0.f);
    }
}

// ---------------- launch ----------------

extern "C" void kernel_launch(void* const* d_in, const int* in_sizes, int n_in,
                              void* d_out, int out_size, void* d_ws, size_t ws_size,
                              hipStream_t stream) {
    const float* node_feat = (const float*)d_in[0];
    const float* edge_feat = (const float*)d_in[1];
    const int*   eidx      = (const int*)d_in[2];
    const float* W0 = (const float*)d_in[3];
    const float* b0 = (const float*)d_in[4];
    const float* W1 = (const float*)d_in[5];
    const float* b1 = (const float*)d_in[6];
    const float* W2 = (const float*)d_in[7];
    const float* b2 = (const float*)d_in[8];
    const float* W3 = (const float*)d_in[9];
    const float* b3 = (const float*)d_in[10];
    const float* wc1 = (const float*)d_in[11];
    const float* bc1 = (const float*)d_in[12];
    const float* wc2 = (const float*)d_in[13];
    const float* bc2 = (const float*)d_in[14];
    const float* wout = (const float*)d_in[15];
    const float* bout = (const float*)d_in[16];
    float* out = (float*)d_out;

    const int* src = eidx;
    const int* dst = eidx + N_EDGES;

    char* ws = (char*)d_ws;
    size_t off = 0;
    auto alloc = [&](size_t bytes) -> char* {
        char* p = ws + off;
        off += (bytes + 255) & ~(size_t)255;
        return p;
    };
    int* cnt       = (int*)alloc((size_t)N_NODES * 4);
    int* row_start = (int*)alloc((size_t)N_NODES * 4);
    int* cursor    = (int*)alloc((size_t)N_NODES * 4);
    int* blocksum  = (int*)alloc(512 * 4);
    int2* csr      = (int2*)alloc((size_t)N_EDGES * 8);
    float* esum    = (float*)alloc((size_t)N_NODES * 32 * 4);
    float* z0      = (float*)alloc((size_t)N_NODES * 32 * 4);
    float* z1      = (float*)alloc((size_t)N_NODES * 32 * 4);
    float* z2      = (float*)alloc((size_t)N_NODES * 32 * 4);
    float* h0      = (float*)alloc((size_t)N_NODES * 32 * 4);
    float* h1      = (float*)alloc((size_t)N_NODES * 32 * 4);
    float* h2      = (float*)alloc((size_t)N_NODES * 32 * 4);
    float* z3      = (float*)alloc((size_t)N_NODES * 4);
    float* val     = (float*)alloc((size_t)N_NODES * 4);
    (void)ws_size;

    k_zero<<<N_NODES / 256, 256, 0, stream>>>(cnt);
    k_count<<<N_EDGES / 256, 256, 0, stream>>>(dst, cnt);
    k_scan1<<<N_NODES / 256, 256, 0, stream>>>(cnt, row_start, blocksum);
    k_scan2<<<1, 512, 0, stream>>>(blocksum);
    k_scan3<<<N_NODES / 256, 256, 0, stream>>>(row_start, blocksum, cursor);
    k_fill<<<N_EDGES / 256, 256, 0, stream>>>(src, dst, cursor, csr);
    k_esum<<<N_NODES / 32, 256, 0, stream>>>(edge_feat, row_start, cnt, csr, esum);
    k_gemm160<<<N_NODES / 64, 256, 0, stream>>>(node_feat, esum, W0, z0);
    k_layer<<<N_NODES / 32, 256, 0, stream>>>(z0, row_start, cnt, csr, b0, W1, h0, z1);
    k_layer<<<N_NODES / 32, 256, 0, stream>>>(z1, row_start, cnt, csr, b1, W2, h1, z2);
    k_layer3<<<N_NODES / 32, 256, 0, stream>>>(z2, row_start, cnt, csr, b2, W3, h2, z3);
    k_g3<<<N_NODES / 256, 256, 0, stream>>>(z3, row_start, cnt, csr, b3, val);
    k_head<<<B_GR, 256, 0, stream>>>(h0, h1, h2, val, wc1, bc1, wc2, bc2, wout, bout, out);
}

// Round 3
// 582.164 us; speedup vs baseline: 1.1510x; 1.0281x over previous
//
#include <hip/hip_runtime.h>
#include <hip/hip_bf16.h>
#include <math.h>

#define N_NODES 131072
#define N_EDGES 1048576
#define B_GR    128
#define NPG_    1024
#define KTOP    30

// ---------------- CSR build ----------------

__global__ __launch_bounds__(256) void k_zero(int* cnt) {
    int i = blockIdx.x * 256 + threadIdx.x;
    if (i < N_NODES) cnt[i] = 0;
}

// XCD-sliced count: blocks with blockIdx&7==x handle dst-slice x (dst>>14).
// Every XCD-group scans the full edge list (nontemporal), so cnt atomics are
// XCD-local and merge in that XCD's L2.
__global__ __launch_bounds__(256) void k_count(const int* __restrict__ dst, int* __restrict__ cnt) {
    int xcd = blockIdx.x & 7;
    int base = (blockIdx.x >> 3) * 4096 + threadIdx.x;
    #pragma unroll
    for (int it = 0; it < 16; ++it) {
        int e = base + it * 256;
        int d = __builtin_nontemporal_load(dst + e);
        if ((d >> 14) == xcd) atomicAdd(&cnt[d], 1);
    }
}

__global__ __launch_bounds__(256) void k_scan1(const int* __restrict__ cnt,
                                               int* __restrict__ row_start,
                                               int* __restrict__ blocksum) {
    __shared__ int s[256];
    int t = threadIdx.x;
    int i = blockIdx.x * 256 + t;
    int v = cnt[i];
    s[t] = v; __syncthreads();
    for (int o = 1; o < 256; o <<= 1) {
        int x = (t >= o) ? s[t - o] : 0;
        __syncthreads();
        s[t] += x;
        __syncthreads();
    }
    row_start[i] = s[t] - v;
    if (t == 255) blocksum[blockIdx.x] = s[t];
}

__global__ __launch_bounds__(512) void k_scan2(int* __restrict__ blocksum) {
    __shared__ int s[512];
    int t = threadIdx.x;
    int v = blocksum[t];
    s[t] = v; __syncthreads();
    for (int o = 1; o < 512; o <<= 1) {
        int x = (t >= o) ? s[t - o] : 0;
        __syncthreads();
        s[t] += x;
        __syncthreads();
    }
    blocksum[t] = s[t] - v;
}

__global__ __launch_bounds__(256) void k_scan3(int* __restrict__ row_start,
                                               const int* __restrict__ blocksum,
                                               int* __restrict__ cursor) {
    int i = blockIdx.x * 256 + threadIdx.x;
    int r = row_start[i] + blocksum[blockIdx.x];
    row_start[i] = r;
    cursor[i] = r;
}

// XCD-sliced fill: same partition as k_count. All writes/atomics for a given
// CSR line come from one XCD -> merge in its L2 before writeback.
// csr split into two int arrays (src for layers, eid for esum) so each
// consumer reads dense 4-B entries.
__global__ __launch_bounds__(256) void k_fill(const int* __restrict__ src,
                                              const int* __restrict__ dst,
                                              int* __restrict__ cursor,
                                              int* __restrict__ csr_src,
                                              int* __restrict__ csr_eid) {
    int xcd = blockIdx.x & 7;
    int base = (blockIdx.x >> 3) * 4096 + threadIdx.x;
    #pragma unroll
    for (int it = 0; it < 16; ++it) {
        int e = base + it * 256;
        int d = __builtin_nontemporal_load(dst + e);
        if ((d >> 14) == xcd) {
            int s = __builtin_nontemporal_load(src + e);
            int pos = atomicAdd(&cursor[d], 1);
            csr_src[pos] = s;
            csr_eid[pos] = e;
        }
    }
}

// ---------------- esum[n][32] = sum of incident edge_feat rows ----------------
// 4 nodes per 32-lane group; all id loads then all row gathers issued
// back-to-back => ~64 cache lines in flight per wave during the burst.

__global__ __launch_bounds__(256) void k_esum(const float* __restrict__ ef,
                                              const int* __restrict__ row_start,
                                              const int* __restrict__ cnt,
                                              const int* __restrict__ csr_eid,
                                              float* __restrict__ esum) {
    int g = threadIdx.x >> 5, j = threadIdx.x & 31;
    int n0 = (blockIdx.x * 8 + g) * 4;
    int st[4], ln[4];
    #pragma unroll
    for (int i = 0; i < 4; ++i) { st[i] = row_start[n0 + i]; ln[i] = cnt[n0 + i]; }
    float acc[4] = {0.f, 0.f, 0.f, 0.f};
    int base = 0;
    while ((ln[0] > base) | (ln[1] > base) | (ln[2] > base) | (ln[3] > base)) {
        int eid[4][8];
        #pragma unroll
        for (int i = 0; i < 4; ++i) {
            #pragma unroll
            for (int s = 0; s < 8; ++s) {
                int idx = base + s;
                int a = st[i] + ((idx < ln[i]) ? idx : 0);
                a = (a < N_EDGES) ? a : 0;
                eid[i][s] = csr_eid[a];        // uniform within group
            }
        }
        #pragma unroll
        for (int i = 0; i < 4; ++i) {
            #pragma unroll
            for (int s = 0; s < 8; ++s) {
                float v = ef[(size_t)eid[i][s] * 32 + j];
                acc[i] += ((base + s) < ln[i]) ? v : 0.f;
            }
        }
        base += 8;
    }
    #pragma unroll
    for (int i = 0; i < 4; ++i)
        esum[(size_t)(n0 + i) * 32 + j] = acc[i];
}

// ---------------- z0 = [nf | esum] @ W0   (K=160, SGPR weights, lane=node)

__global__ __launch_bounds__(256) void k_gemm160(const float* __restrict__ nf,
                                                 const float* __restrict__ esum,
                                                 const float* __restrict__ W0,
                                                 float* __restrict__ z0) {
    __shared__ float a[64 * 161];
    int tid = threadIdx.x;
    int n0 = blockIdx.x * 64;
    const float* nfb = nf + (size_t)n0 * 128;
    for (int f = tid; f < 8192; f += 256) {
        int n = f >> 7, k = f & 127;
        a[n * 161 + k] = nfb[f];
    }
    const float* esb = esum + (size_t)n0 * 32;
    for (int f = tid; f < 2048; f += 256) {
        int n = f >> 5, k = f & 31;
        a[n * 161 + 128 + k] = esb[f];
    }
    __syncthreads();
    int wv = __builtin_amdgcn_readfirstlane(tid >> 6);
    int lane = tid & 63;
    int c0 = wv * 8;
    float acc[8] = {0.f, 0.f, 0.f, 0.f, 0.f, 0.f, 0.f, 0.f};
    const float* ar = a + lane * 161;
    for (int k = 0; k < 160; ++k) {
        float av = ar[k];
        #pragma unroll
        for (int jj = 0; jj < 8; ++jj)
            acc[jj] += av * W0[k * 32 + c0 + jj];
    }
    float* zr = z0 + (size_t)(n0 + lane) * 32 + c0;
    *(float4*)zr = make_float4(acc[0], acc[1], acc[2], acc[3]);
    *(float4*)(zr + 4) = make_float4(acc[4], acc[5], acc[6], acc[7]);
}

// ---------------- fused propagation layer ----------------
// h = tanh((z_self + sum z_nb + b)/deg) ; z_next = h @ Wn
// 4 nodes per 32-lane group (lane = feature); batched id+gather rounds;
// gemm fused via lane-broadcast shuffles against LDS-staged Wn.

__global__ __launch_bounds__(256) void k_layer(const float* __restrict__ zin,
                                               const int* __restrict__ row_start,
                                               const int* __restrict__ cnt,
                                               const int* __restrict__ csr_src,
                                               const float* __restrict__ bias,
                                               const float* __restrict__ Wn,
                                               float* __restrict__ hout,
                                               float* __restrict__ znext) {
    __shared__ float Ws[1024];
    int tid = threadIdx.x;
    for (int f = tid; f < 1024; f += 256) Ws[f] = Wn[f];
    __syncthreads();
    int g = tid >> 5, j = tid & 31;
    int n0 = (blockIdx.x * 8 + g) * 4;
    int st[4], ln[4];
    #pragma unroll
    for (int i = 0; i < 4; ++i) { st[i] = row_start[n0 + i]; ln[i] = cnt[n0 + i]; }
    float acc[4];
    #pragma unroll
    for (int i = 0; i < 4; ++i) acc[i] = zin[(size_t)(n0 + i) * 32 + j];  // self
    int base = 0;
    while ((ln[0] > base) | (ln[1] > base) | (ln[2] > base) | (ln[3] > base)) {
        int sid[4][8];
        #pragma unroll
        for (int i = 0; i < 4; ++i) {
            #pragma unroll
            for (int s = 0; s < 8; ++s) {
                int idx = base + s;
                int a = st[i] + ((idx < ln[i]) ? idx : 0);
                a = (a < N_EDGES) ? a : 0;
                sid[i][s] = csr_src[a];        // src node id, uniform within group
            }
        }
        #pragma unroll
        for (int i = 0; i < 4; ++i) {
            #pragma unroll
            for (int s = 0; s < 8; ++s) {
                float v = zin[(size_t)sid[i][s] * 32 + j];
                acc[i] += ((base + s) < ln[i]) ? v : 0.f;
            }
        }
        base += 8;
    }
    float bj = bias[j];
    float h[4];
    #pragma unroll
    for (int i = 0; i < 4; ++i) {
        float deg = 1.f + (float)ln[i];
        h[i] = tanhf((acc[i] + bj) / deg);
        hout[(size_t)(n0 + i) * 32 + j] = h[i];
    }
    float z[4] = {0.f, 0.f, 0.f, 0.f};
    for (int k = 0; k < 32; ++k) {
        float w = Ws[k * 32 + j];
        #pragma unroll
        for (int i = 0; i < 4; ++i)
            z[i] += __shfl(h[i], k, 32) * w;
    }
    #pragma unroll
    for (int i = 0; i < 4; ++i)
        znext[(size_t)(n0 + i) * 32 + j] = z[i];
}

// ---------------- last 32-wide layer: h2 + scalar z3 = h2 @ W3 ----------------

__global__ __launch_bounds__(256) void k_layer3(const float* __restrict__ zin,
                                                const int* __restrict__ row_start,
                                                const int* __restrict__ cnt,
                                                const int* __restrict__ csr_src,
                                                const float* __restrict__ bias,
                                                const float* __restrict__ W3,
                                                float* __restrict__ hout,
                                                float* __restrict__ z3) {
    int g = threadIdx.x >> 5, j = threadIdx.x & 31;
    int n0 = (blockIdx.x * 8 + g) * 4;
    int st[4], ln[4];
    #pragma unroll
    for (int i = 0; i < 4; ++i) { st[i] = row_start[n0 + i]; ln[i] = cnt[n0 + i]; }
    float acc[4];
    #pragma unroll
    for (int i = 0; i < 4; ++i) acc[i] = zin[(size_t)(n0 + i) * 32 + j];
    int base = 0;
    while ((ln[0] > base) | (ln[1] > base) | (ln[2] > base) | (ln[3] > base)) {
        int sid[4][8];
        #pragma unroll
        for (int i = 0; i < 4; ++i) {
            #pragma unroll
            for (int s = 0; s < 8; ++s) {
                int idx = base + s;
                int a = st[i] + ((idx < ln[i]) ? idx : 0);
                a = (a < N_EDGES) ? a : 0;
                sid[i][s] = csr_src[a];
            }
        }
        #pragma unroll
        for (int i = 0; i < 4; ++i) {
            #pragma unroll
            for (int s = 0; s < 8; ++s) {
                float v = zin[(size_t)sid[i][s] * 32 + j];
                acc[i] += ((base + s) < ln[i]) ? v : 0.f;
            }
        }
        base += 8;
    }
    float bj = bias[j];
    float w3 = W3[j];
    #pragma unroll
    for (int i = 0; i < 4; ++i) {
        float deg = 1.f + (float)ln[i];
        float h = tanhf((acc[i] + bj) / deg);
        hout[(size_t)(n0 + i) * 32 + j] = h;
        float t = h * w3;
        #pragma unroll
        for (int o = 16; o; o >>= 1) t += __shfl_xor(t, o, 32);
        if (j == 0) z3[n0 + i] = t;
    }
}

// ---------------- layer 3: scalar gather-sum -> val ----------------

__global__ __launch_bounds__(256) void k_g3(const float* __restrict__ z3,
                                            const int* __restrict__ row_start,
                                            const int* __restrict__ cnt,
                                            const int* __restrict__ csr_src,
                                            const float* __restrict__ b3,
                                            float* __restrict__ val) {
    int n = blockIdx.x * 256 + threadIdx.x;
    int start = row_start[n], len = cnt[n];
    const int* cs = csr_src + start;
    float s = z3[n];
    int i = 0;
    for (; i + 4 <= len; i += 4)
        s += z3[cs[i]] + z3[cs[i + 1]] + z3[cs[i + 2]] + z3[cs[i + 3]];
    for (; i < len; ++i) s += z3[cs[i]];
    float deg = 1.f + (float)len;
    val[n] = tanhf((s + b3[0]) / deg);
}

// ---------------- top-k + conv head, one block per graph ----------------

__global__ __launch_bounds__(256) void k_head(const float* __restrict__ h0,
                                              const float* __restrict__ h1,
                                              const float* __restrict__ h2,
                                              const float* __restrict__ val,
                                              const float* __restrict__ wc1,
                                              const float* __restrict__ bc1,
                                              const float* __restrict__ wc2,
                                              const float* __restrict__ bc2,
                                              const float* __restrict__ wout,
                                              const float* __restrict__ bout,
                                              float* __restrict__ out) {
    __shared__ float vals[1024];
    __shared__ int selidx[KTOP];
    __shared__ float sp[KTOP * 97];
    __shared__ float y1[16 * 30];
    __shared__ float pool[16 * 15];
    __shared__ float y2[352];
    int b = blockIdx.x, tid = threadIdx.x;
    const float* vb = val + (size_t)b * NPG_;
    for (int u = tid; u < NPG_; u += 256) vals[u] = vb[u];
    __syncthreads();
    if (tid < 64) {
        unsigned long long keys[16];
        #pragma unroll
        for (int r = 0; r < 16; ++r) {
            int u = tid * 16 + r;
            unsigned int bb = __float_as_uint(vals[u]);
            unsigned int ord = (bb & 0x80000000u) ? ~bb : (bb | 0x80000000u);
            keys[r] = ((unsigned long long)ord << 32) |
                      (unsigned long long)(0xFFFFFFFFu - (unsigned int)u);
        }
        for (int k = 0; k < KTOP; ++k) {
            unsigned long long m = keys[0];
            #pragma unroll
            for (int r = 1; r < 16; ++r) m = (keys[r] > m) ? keys[r] : m;
            #pragma unroll
            for (int o = 32; o; o >>= 1) {
                unsigned long long t = __shfl_xor(m, o);
                m = (t > m) ? t : m;
            }
            int u = (int)(0xFFFFFFFFu - (unsigned int)(m & 0xFFFFFFFFull));
            if (tid == 0) selidx[k] = u;
            #pragma unroll
            for (int r = 0; r < 16; ++r)
                if (tid * 16 + r == u) keys[r] = 0ull;
        }
    }
    __syncthreads();
    size_t nb = (size_t)b * NPG_;
    for (int idx = tid; idx < KTOP * 32; idx += 256) {
        int t = idx >> 5, d = idx & 31;
        size_t s = (nb + (size_t)selidx[t]) * 32;
        sp[t * 97 + d]      = h0[s + d];
        sp[t * 97 + 32 + d] = h1[s + d];
        sp[t * 97 + 64 + d] = h2[s + d];
    }
    if (tid < KTOP) sp[tid * 97 + 96] = vb[selidx[tid]];
    __syncthreads();
    for (int idx = tid; idx < 480; idx += 256) {
        int t = idx >> 4, c = idx & 15;
        float acc = bc1[c];
        for (int d = 0; d < 97; ++d) acc += sp[t * 97 + d] * wc1[c * 97 + d];
        y1[c * 30 + t] = fmaxf(acc, 0.f);
    }
    __syncthreads();
    for (int idx = tid; idx < 240; idx += 256) {
        int c = idx / 15, u = idx - c * 15;
        pool[c * 15 + u] = fmaxf(y1[c * 30 + 2 * u], y1[c * 30 + 2 * u + 1]);
    }
    __syncthreads();
    for (int idx = tid; idx < 352; idx += 256) {
        int o = idx / 11, t = idx - o * 11;
        float acc = bc2[o];
        for (int i = 0; i < 16; ++i)
            for (int kk = 0; kk < 5; ++kk)
                acc += pool[i * 15 + t + kk] * wc2[(o * 16 + i) * 5 + kk];
        y2[idx] = fmaxf(acc, 0.f);
    }
    __syncthreads();
    if (tid < 2) {
        float acc = bout[tid];
        for (int m = 0; m < 352; ++m) acc += y2[m] * wout[m * 2 + tid];
        out[b * 2 + tid] = fmaxf(acc, 0.f);
    }
}

// ---------------- launch ----------------

extern "C" void kernel_launch(void* const* d_in, const int* in_sizes, int n_in,
                              void* d_out, int out_size, void* d_ws, size_t ws_size,
                              hipStream_t stream) {
    const float* node_feat = (const float*)d_in[0];
    const float* edge_feat = (const float*)d_in[1];
    const int*   eidx      = (const int*)d_in[2];
    const float* W0 = (const float*)d_in[3];
    const float* b0 = (const float*)d_in[4];
    const float* W1 = (const float*)d_in[5];
    const float* b1 = (const float*)d_in[6];
    const float* W2 = (const float*)d_in[7];
    const float* b2 = (const float*)d_in[8];
    const float* W3 = (const float*)d_in[9];
    const float* b3 = (const float*)d_in[10];
    const float* wc1 = (const float*)d_in[11];
    const float* bc1 = (const float*)d_in[12];
    const float* wc2 = (const float*)d_in[13];
    const float* bc2 = (const float*)d_in[14];
    const float* wout = (const float*)d_in[15];
    const float* bout = (const float*)d_in[16];
    float* out = (float*)d_out;

    const int* src = eidx;
    const int* dst = eidx + N_EDGES;

    char* ws = (char*)d_ws;
    size_t off = 0;
    auto alloc = [&](size_t bytes) -> char* {
        char* p = ws + off;
        off += (bytes + 255) & ~(size_t)255;
        return p;
    };
    int* cnt       = (int*)alloc((size_t)N_NODES * 4);
    int* row_start = (int*)alloc((size_t)N_NODES * 4);
    int* cursor    = (int*)alloc((size_t)N_NODES * 4);
    int* blocksum  = (int*)alloc(512 * 4);
    int* csr_src   = (int*)alloc((size_t)N_EDGES * 4);
    int* csr_eid   = (int*)alloc((size_t)N_EDGES * 4);
    float* esum    = (float*)alloc((size_t)N_NODES * 32 * 4);
    float* z0      = (float*)alloc((size_t)N_NODES * 32 * 4);
    float* z1      = (float*)alloc((size_t)N_NODES * 32 * 4);
    float* z2      = (float*)alloc((size_t)N_NODES * 32 * 4);
    float* h0      = (float*)alloc((size_t)N_NODES * 32 * 4);
    float* h1      = (float*)alloc((size_t)N_NODES * 32 * 4);
    float* h2      = (float*)alloc((size_t)N_NODES * 32 * 4);
    float* z3      = (float*)alloc((size_t)N_NODES * 4);
    float* val     = (float*)alloc((size_t)N_NODES * 4);
    (void)ws_size;

    k_zero<<<N_NODES / 256, 256, 0, stream>>>(cnt);
    k_count<<<2048, 256, 0, stream>>>(dst, cnt);
    k_scan1<<<N_NODES / 256, 256, 0, stream>>>(cnt, row_start, blocksum);
    k_scan2<<<1, 512, 0, stream>>>(blocksum);
    k_scan3<<<N_NODES / 256, 256, 0, stream>>>(row_start, blocksum, cursor);
    k_fill<<<2048, 256, 0, stream>>>(src, dst, cursor, csr_src, csr_eid);
    k_esum<<<N_NODES / 32, 256, 0, stream>>>(edge_feat, row_start, cnt, csr_eid, esum);
    k_gemm160<<<N_NODES / 64, 256, 0, stream>>>(node_feat, esum, W0, z0);
    k_layer<<<N_NODES / 32, 256, 0, stream>>>(z0, row_start, cnt, csr_src, b0, W1, h0, z1);
    k_layer<<<N_NODES / 32, 256, 0, stream>>>(z1, row_start, cnt, csr_src, b1, W2, h1, z2);
    k_layer3<<<N_NODES / 32, 256, 0, stream>>>(z2, row_start, cnt, csr_src, b2, W3, h2, z3);
    k_g3<<<N_NODES / 256, 256, 0, stream>>>(z3, row_start, cnt, csr_src, b3, val);
    k_head<<<B_GR, 256, 0, stream>>>(h0, h1, h2, val, wc1, bc1, wc2, bc2, wout, bout, out);
}